// Round 5
// baseline (1171.256 us; speedup 1.0000x reference)
//
#include <hip/hip_runtime.h>
#include <hip/hip_bf16.h>

typedef unsigned int  u32;
typedef unsigned short u16;

typedef __bf16 bf16x8 __attribute__((ext_vector_type(8)));
typedef float  f32x4  __attribute__((ext_vector_type(4)));

#define D2048 2048
#define SCALE 0.022097086912079612f

__device__ __forceinline__ u32 f2bfbits(float f) {
    u32 u = __float_as_uint(f);
    return (u + 0x7FFFu + ((u >> 16) & 1u)) >> 16;   // RNE
}
__device__ __forceinline__ u32 pack2(float a, float b) {
    return f2bfbits(a) | (f2bfbits(b) << 16);
}
__device__ __forceinline__ float bf2f(u32 h) {
    return __uint_as_float(h << 16);
}
__device__ __forceinline__ void unpack8(uint4 v, float* f) {
    f[0] = bf2f(v.x & 0xFFFFu); f[1] = bf2f(v.x >> 16);
    f[2] = bf2f(v.y & 0xFFFFu); f[3] = bf2f(v.y >> 16);
    f[4] = bf2f(v.z & 0xFFFFu); f[5] = bf2f(v.z >> 16);
    f[6] = bf2f(v.w & 0xFFFFu); f[7] = bf2f(v.w >> 16);
}
__device__ __forceinline__ float sigmf(float x) { return 1.f / (1.f + __expf(-x)); }
__device__ __forceinline__ float tanhf_(float x) {
    x = fminf(15.f, fmaxf(-15.f, x));
    float e = __expf(2.f * x);
    return (e - 1.f) / (e + 1.f);
}

// async global->LDS, 16B per lane. LDS dest: wave-uniform base + lane*16B.
__device__ __forceinline__ void gload_lds16(const u16* g, u16* l) {
    __builtin_amdgcn_global_load_lds(
        (const __attribute__((address_space(1))) unsigned int*)g,
        (__attribute__((address_space(3))) unsigned int*)l,
        16, 0, 0);
}

// ---------------------------------------------------------------------------
// Multi-segment fp32 -> bf16 conversion (grid-stride per segment)
// ---------------------------------------------------------------------------
struct CvtArgs {
    const float* src[8];
    u16*         dst[8];
    int          n4[8];
    int          nseg;
};
__global__ __launch_bounds__(256) void cvt_multi(CvtArgs a) {
    int stride = gridDim.x * 256;
    for (int s = 0; s < a.nseg; ++s) {
        const float4* S = reinterpret_cast<const float4*>(a.src[s]);
        uint2*        D = reinterpret_cast<uint2*>(a.dst[s]);
        int n4 = a.n4[s];
        for (int i = blockIdx.x * 256 + threadIdx.x; i < n4; i += stride) {
            float4 v = S[i];
            uint2 p;
            p.x = pack2(v.x, v.y);
            p.y = pack2(v.z, v.w);
            D[i] = p;
        }
    }
}

// ---------------------------------------------------------------------------
// 256x256 8-phase GEMM (bank-conflict-free XOR swizzle, counted vmcnt).
// C[M][N] = A[M][K](bf16, stride lda) * B[N][K](bf16)^T, bf16 or f32 out.
// ---------------------------------------------------------------------------
template <bool OUT_BF16>
__global__ __launch_bounds__(512, 2) void gemm256(const u16* __restrict__ A, int lda,
                                                  const u16* __restrict__ B,
                                                  void* __restrict__ C0,
                                                  int M, int N, int K) {
    __shared__ u16 Ab[2][16384];
    __shared__ u16 Bb[2][16384];

    const int tid  = threadIdx.x;
    const int lane = tid & 63;
    const int wid  = tid >> 6;       // 0..7
    const int wm   = wid >> 2;       // 0..1
    const int wn   = wid & 3;        // 0..3
    const int l15  = lane & 15, l4 = lane >> 4;
    const int rowBase = blockIdx.y * 256;
    const int colBase = blockIdx.x * 256;

    // staging source (pre-swizzled: LDS chunk c' holds global chunk c'^(row&7))
    const int srow8 = lane >> 3;                   // row-within-8 (== row&7)
    const int scw   = ((lane & 7) ^ srow8) * 8;    // swizzled 16B chunk -> elems
    const u16* gA = A + (size_t)(rowBase + wid * 8 + srow8) * lda + scw;
    const u16* gB = B + (size_t)(colBase + wid * 8 + srow8) * (size_t)K + scw;
    const int ldsW = wid * 512;                    // wave base within 64-row chunk

#define STAGE_A(buf, koff, q) \
    gload_lds16(gA + (size_t)((q) * 64) * lda + (koff), &Ab[buf][(q) * 4096 + ldsW])
#define STAGE_B(buf, koff, q) \
    gload_lds16(gB + (size_t)((q) * 64) * (size_t)K + (koff), &Bb[buf][(q) * 4096 + ldsW])

    f32x4 acc[8][4];
#pragma unroll
    for (int m = 0; m < 8; m++)
#pragma unroll
        for (int n = 0; n < 4; n++) acc[m][n] = f32x4{0.f, 0.f, 0.f, 0.f};

    const int nt = K >> 6;

#pragma unroll
    for (int q = 0; q < 4; ++q) { STAGE_A(0, 0, q); STAGE_B(0, 0, q); }

    const int swzA = (l15 & 7);  // row&7 for all frag rows (row ≡ l15 mod 16)

    for (int t = 0; t < nt; ++t) {
        const int cur = t & 1;
        const int nxt = cur ^ 1;
        const int kN  = (t + 1) << 6;
        const bool more = (t + 1 < nt);

        if (more) {
            STAGE_A(nxt, kN, 0);
            STAGE_A(nxt, kN, 1);
            asm volatile("s_waitcnt vmcnt(2)" ::: "memory");
        } else {
            asm volatile("s_waitcnt vmcnt(0)" ::: "memory");
        }
        __builtin_amdgcn_s_barrier();

        bf16x8 bfrag[4][2];
#pragma unroll
        for (int n = 0; n < 4; ++n)
#pragma unroll
            for (int kk = 0; kk < 2; ++kk)
                bfrag[n][kk] = *reinterpret_cast<const bf16x8*>(
                    &Bb[cur][(wn * 64 + n * 16 + l15) * 64 +
                             (((kk * 4 + l4) ^ swzA) * 8)]);

#pragma unroll
        for (int p = 0; p < 4; ++p) {
            bf16x8 afr[2][2];
#pragma unroll
            for (int mi = 0; mi < 2; ++mi)
#pragma unroll
                for (int kk = 0; kk < 2; ++kk)
                    afr[mi][kk] = *reinterpret_cast<const bf16x8*>(
                        &Ab[cur][(wm * 128 + (p * 2 + mi) * 16 + l15) * 64 +
                                 (((kk * 4 + l4) ^ swzA) * 8)]);
            if (more) {
                if (p == 0)      { STAGE_A(nxt, kN, 2); STAGE_A(nxt, kN, 3); }
                else if (p == 1) { STAGE_B(nxt, kN, 0); STAGE_B(nxt, kN, 1); }
                else if (p == 2) { STAGE_B(nxt, kN, 2); STAGE_B(nxt, kN, 3); }
            }
            __builtin_amdgcn_s_barrier();
            __builtin_amdgcn_sched_barrier(0);
            __builtin_amdgcn_s_setprio(1);
#pragma unroll
            for (int kk = 0; kk < 2; ++kk)
#pragma unroll
                for (int mi = 0; mi < 2; ++mi)
#pragma unroll
                    for (int n = 0; n < 4; ++n)
                        acc[p * 2 + mi][n] = __builtin_amdgcn_mfma_f32_16x16x32_bf16(
                            afr[mi][kk], bfrag[n][kk], acc[p * 2 + mi][n], 0, 0, 0);
            __builtin_amdgcn_s_setprio(0);
            __builtin_amdgcn_sched_barrier(0);
            __builtin_amdgcn_s_barrier();
        }
    }
#undef STAGE_A
#undef STAGE_B

#pragma unroll
    for (int m = 0; m < 8; ++m) {
        int row0 = rowBase + wm * 128 + m * 16 + l4 * 4;
#pragma unroll
        for (int n = 0; n < 4; ++n) {
            int col = colBase + wn * 64 + n * 16 + l15;
#pragma unroll
            for (int rr = 0; rr < 4; ++rr) {
                if (OUT_BF16)
                    ((u16*)C0)[(size_t)(row0 + rr) * N + col] = (u16)f2bfbits(acc[m][n][rr]);
                else
                    ((float*)C0)[(size_t)(row0 + rr) * N + col] = acc[m][n][rr];
            }
        }
    }
}

// ---------------------------------------------------------------------------
// QKV GEMM: 128x128 tile, BK=64, 4 waves, 2-phase dbuf, grid.z selects panel.
// ---------------------------------------------------------------------------
__global__ __launch_bounds__(256) void gemm_qkv(const u16* __restrict__ A,
                                                const u16* __restrict__ B0,
                                                const u16* __restrict__ B1,
                                                const u16* __restrict__ B2,
                                                const float* __restrict__ bias0,
                                                const float* __restrict__ bias1,
                                                const float* __restrict__ bias2,
                                                u16* __restrict__ Cout,
                                                size_t zCstride,
                                                int M, int N, int K) {
    __shared__ u16 Abuf[2][128 * 64];
    __shared__ u16 Bbuf[2][128 * 64];

    const int tid  = threadIdx.x;
    const int lane = tid & 63;
    const int wave = tid >> 6;
    const int wr   = (wave >> 1) * 64;
    const int wc   = (wave & 1) * 64;
    const int rowBase = blockIdx.y * 128;
    const int colBase = blockIdx.x * 128;
    const int l15 = lane & 15, l4 = lane >> 4;
    const int srow = lane >> 3;
    const int scol = (lane & 7) * 8;

    const int z = blockIdx.z;
    const u16* B      = (z == 0) ? B0 : ((z == 1) ? B1 : B2);
    const float* bias = (z == 0) ? bias0 : ((z == 1) ? bias1 : bias2);
    u16* C = Cout + (size_t)z * zCstride;

    const u16* ga = A + (size_t)(rowBase + wave * 32 + srow) * K + scol;
    const u16* gb = B + (size_t)(colBase + wave * 32 + srow) * K + scol;
    const int ldsOff = (wave * 32) * 64;

    f32x4 acc[4][4];
#pragma unroll
    for (int i = 0; i < 4; i++)
#pragma unroll
        for (int j = 0; j < 4; j++) acc[i][j] = f32x4{0.f, 0.f, 0.f, 0.f};

    const int nt = K >> 6;

#pragma unroll
    for (int i = 0; i < 4; ++i) {
        gload_lds16(ga + (size_t)(i * 8) * K, &Abuf[0][ldsOff + i * 8 * 64]);
        gload_lds16(gb + (size_t)(i * 8) * K, &Bbuf[0][ldsOff + i * 8 * 64]);
    }

    for (int t = 0; t < nt; ++t) {
        const int cur = t & 1;
        if (t + 1 < nt) {
            const int k1 = (t + 1) << 6;
#pragma unroll
            for (int i = 0; i < 4; ++i) {
                gload_lds16(ga + (size_t)(i * 8) * K + k1,
                            &Abuf[cur ^ 1][ldsOff + i * 8 * 64]);
                gload_lds16(gb + (size_t)(i * 8) * K + k1,
                            &Bbuf[cur ^ 1][ldsOff + i * 8 * 64]);
            }
            asm volatile("s_waitcnt vmcnt(8)" ::: "memory");
        } else {
            asm volatile("s_waitcnt vmcnt(0)" ::: "memory");
        }
        __builtin_amdgcn_s_barrier();
        __builtin_amdgcn_sched_barrier(0);
#pragma unroll
        for (int kk = 0; kk < 2; ++kk) {
            bf16x8 af[4], bfr[4];
#pragma unroll
            for (int i = 0; i < 4; i++) {
                af[i]  = *reinterpret_cast<const bf16x8*>(
                    &Abuf[cur][(wr + i * 16 + l15) * 64 + kk * 32 + l4 * 8]);
                bfr[i] = *reinterpret_cast<const bf16x8*>(
                    &Bbuf[cur][(wc + i * 16 + l15) * 64 + kk * 32 + l4 * 8]);
            }
#pragma unroll
            for (int i = 0; i < 4; i++)
#pragma unroll
                for (int j = 0; j < 4; j++)
                    acc[i][j] = __builtin_amdgcn_mfma_f32_16x16x32_bf16(af[i], bfr[j],
                                                                        acc[i][j], 0, 0, 0);
        }
        __builtin_amdgcn_sched_barrier(0);
        __builtin_amdgcn_s_barrier();
    }

#pragma unroll
    for (int i = 0; i < 4; i++) {
        int row0 = rowBase + wr + i * 16 + l4 * 4;
#pragma unroll
        for (int j = 0; j < 4; j++) {
            int col = colBase + wc + j * 16 + l15;
            float bv = bias[col];
#pragma unroll
            for (int rr = 0; rr < 4; rr++)
                C[(size_t)(row0 + rr) * N + col] = (u16)f2bfbits(acc[i][j][rr] + bv);
        }
    }
}

// ---------------------------------------------------------------------------
// Fused recurrent GEMM + LSTM gate, 128-row tile (nsa loop).
// Block (jb, rb): rows rb*128 (windows), 32 hidden-j x 4 gates (128 cols).
// B rows gathered: localcol c -> Whh row jb*32 + (c&31) + (c>>5)*2048.
// Full K in registers -> C tile to LDS (reusing dbuf) -> gate math -> c/h.
// ---------------------------------------------------------------------------
template <bool LAST>
__global__ __launch_bounds__(256) void gemm_gate128(
    const u16* __restrict__ A,      // h_{t-1} bf16 [M][2048]
    const u16* __restrict__ B,      // Whh bf16 [8192][2048]
    const u16* __restrict__ xg,     // xg base for this step; row stride xg_stride
    int xg_stride,
    const float* __restrict__ bih,
    const float* __restrict__ bhh,
    float* __restrict__ c,          // [M][2048] f32, read+write
    u16* __restrict__ hbf_out,      // [M][2048] bf16 (next-step A)
    float* __restrict__ hf,         // f32 h (only when LAST)
    int K) {
    __shared__ u16 smem[32768];     // 64 KB: A dbuf 32KB | B dbuf 32KB; C alias
    u16* Ab = smem;                 // [2][128*64]
    u16* Bb = smem + 16384;

    const int tid = threadIdx.x, lane = tid & 63, wave = tid >> 6;
    const int wr = (wave >> 1) * 64, wc = (wave & 1) * 64;
    const int l15 = lane & 15, l4 = lane >> 4;
    const int srow = lane >> 3, scol = (lane & 7) * 8;
    const int jBase = blockIdx.x * 32;
    const int rowBase = blockIdx.y * 128;

    const u16* ga = A + (size_t)(rowBase + wave * 32 + srow) * K + scol;
    const u16* gb[4];
#pragma unroll
    for (int i = 0; i < 4; ++i) {
        int lc = wave * 32 + i * 8 + srow;
        int br = jBase + (lc & 31) + (lc >> 5) * 2048;
        gb[i] = B + (size_t)br * K + scol;
    }
    const int ldsOff = (wave * 32) * 64;

    f32x4 acc[4][4];
#pragma unroll
    for (int i = 0; i < 4; i++)
#pragma unroll
        for (int j = 0; j < 4; j++) acc[i][j] = f32x4{0.f, 0.f, 0.f, 0.f};

    const int nt = K >> 6;
#pragma unroll
    for (int i = 0; i < 4; ++i) {
        gload_lds16(ga + (size_t)(i * 8) * K, &Ab[ldsOff + i * 8 * 64]);
        gload_lds16(gb[i], &Bb[ldsOff + i * 8 * 64]);
    }

    for (int t = 0; t < nt; ++t) {
        const int cur = (t & 1) * 8192;
        if (t + 1 < nt) {
            const int k1 = (t + 1) << 6;
            const int nxt = ((t + 1) & 1) * 8192;
#pragma unroll
            for (int i = 0; i < 4; ++i) {
                gload_lds16(ga + (size_t)(i * 8) * K + k1, &Ab[nxt + ldsOff + i * 8 * 64]);
                gload_lds16(gb[i] + k1, &Bb[nxt + ldsOff + i * 8 * 64]);
            }
            asm volatile("s_waitcnt vmcnt(8)" ::: "memory");
        } else {
            asm volatile("s_waitcnt vmcnt(0)" ::: "memory");
        }
        __builtin_amdgcn_s_barrier();
        __builtin_amdgcn_sched_barrier(0);
#pragma unroll
        for (int kk = 0; kk < 2; ++kk) {
            bf16x8 af[4], bfr[4];
#pragma unroll
            for (int i = 0; i < 4; i++) {
                af[i]  = *reinterpret_cast<const bf16x8*>(
                    &Ab[cur + (wr + i * 16 + l15) * 64 + kk * 32 + l4 * 8]);
                bfr[i] = *reinterpret_cast<const bf16x8*>(
                    &Bb[cur + (wc + i * 16 + l15) * 64 + kk * 32 + l4 * 8]);
            }
#pragma unroll
            for (int i = 0; i < 4; i++)
#pragma unroll
                for (int j = 0; j < 4; j++)
                    acc[i][j] = __builtin_amdgcn_mfma_f32_16x16x32_bf16(af[i], bfr[j],
                                                                        acc[i][j], 0, 0, 0);
        }
        __builtin_amdgcn_sched_barrier(0);
        __builtin_amdgcn_s_barrier();
    }

    // --- gate epilogue: C tile (128x128 f32 = 64 KB) overlays the dbuf ---
    float* Cs = (float*)smem;
#pragma unroll
    for (int i = 0; i < 4; i++)
#pragma unroll
        for (int j = 0; j < 4; j++)
#pragma unroll
            for (int rr = 0; rr < 4; rr++)
                Cs[(wr + i * 16 + l4 * 4 + rr) * 128 + (wc + j * 16 + l15)] =
                    acc[i][j][rr];
    __syncthreads();

    const int j  = tid & 31;
    const int rb = tid >> 5;          // 0..7
    const int gj = jBase + j;
    const float bi_ = bih[gj]        + bhh[gj];
    const float bf_ = bih[gj + 2048] + bhh[gj + 2048];
    const float bg_ = bih[gj + 4096] + bhh[gj + 4096];
    const float bo_ = bih[gj + 6144] + bhh[gj + 6144];
#pragma unroll
    for (int k = 0; k < 16; ++k) {
        int r = rb * 16 + k;
        int n = rowBase + r;
        const u16* xr = xg + (size_t)n * xg_stride;
        float gi = Cs[r * 128 + j]      + bf2f((u32)xr[gj])        + bi_;
        float gf = Cs[r * 128 + 32 + j] + bf2f((u32)xr[gj + 2048]) + bf_;
        float gg = Cs[r * 128 + 64 + j] + bf2f((u32)xr[gj + 4096]) + bg_;
        float go = Cs[r * 128 + 96 + j] + bf2f((u32)xr[gj + 6144]) + bo_;
        size_t idx = (size_t)n * 2048 + gj;
        float cc = c[idx];
        float cn = sigmf(gf) * cc + sigmf(gi) * tanhf_(gg);
        float hn = sigmf(go) * tanhf_(cn);
        c[idx] = cn;
        hbf_out[idx] = (u16)f2bfbits(hn);
        if (LAST) hf[idx] = hn;
    }
}

// ---------------------------------------------------------------------------
// Fused recurrent GEMM + gate, 64-row tile (sa loop). Grid (64). Waves own
// rows 0..63 x 32 local cols. Same 4-gate column gather; optional f32 hout.
// ---------------------------------------------------------------------------
__global__ __launch_bounds__(256) void gemm_gate64(
    const u16* __restrict__ A,      // h_{t-1} bf16 [64][2048]
    const u16* __restrict__ B,      // Whh bf16 [8192][2048]
    const u16* __restrict__ xg,     // xg base for this step; row stride xg_stride
    int xg_stride,
    const float* __restrict__ bih,
    const float* __restrict__ bhh,
    float* __restrict__ c,          // [64][2048] f32
    u16* __restrict__ hbf_out,      // [64][2048] bf16
    float* __restrict__ hf,         // optional f32 h (final step) or null
    int K) {
    __shared__ u16 smem[24576];     // 48 KB: A dbuf 16KB | B dbuf 32KB; C alias 32KB
    u16* Ab = smem;                 // [2][64*64]
    u16* Bb = smem + 8192;          // [2][128*64]

    const int tid = threadIdx.x, lane = tid & 63, wave = tid >> 6;
    const int l15 = lane & 15, l4 = lane >> 4;
    const int srow = lane >> 3, scol = (lane & 7) * 8;
    const int jBase = blockIdx.x * 32;

    const u16* ga = A + (size_t)(wave * 16 + srow) * K + scol;
    const u16* gb[4];
#pragma unroll
    for (int i = 0; i < 4; ++i) {
        int lc = wave * 32 + i * 8 + srow;
        int br = jBase + (lc & 31) + (lc >> 5) * 2048;
        gb[i] = B + (size_t)br * K + scol;
    }
    const int laOff = (wave * 16) * 64;
    const int lbOff = (wave * 32) * 64;

    f32x4 acc[4][2];
#pragma unroll
    for (int i = 0; i < 4; i++)
#pragma unroll
        for (int j = 0; j < 2; j++) acc[i][j] = f32x4{0.f, 0.f, 0.f, 0.f};

    const int nt = K >> 6;
#pragma unroll
    for (int i = 0; i < 2; ++i)
        gload_lds16(ga + (size_t)(i * 8) * K, &Ab[laOff + i * 8 * 64]);
#pragma unroll
    for (int i = 0; i < 4; ++i)
        gload_lds16(gb[i], &Bb[lbOff + i * 8 * 64]);

    for (int t = 0; t < nt; ++t) {
        const int curA = (t & 1) * 4096;
        const int curB = (t & 1) * 8192;
        if (t + 1 < nt) {
            const int k1 = (t + 1) << 6;
            const int nxA = ((t + 1) & 1) * 4096;
            const int nxB = ((t + 1) & 1) * 8192;
#pragma unroll
            for (int i = 0; i < 2; ++i)
                gload_lds16(ga + (size_t)(i * 8) * K + k1, &Ab[nxA + laOff + i * 8 * 64]);
#pragma unroll
            for (int i = 0; i < 4; ++i)
                gload_lds16(gb[i] + k1, &Bb[nxB + lbOff + i * 8 * 64]);
            asm volatile("s_waitcnt vmcnt(6)" ::: "memory");
        } else {
            asm volatile("s_waitcnt vmcnt(0)" ::: "memory");
        }
        __builtin_amdgcn_s_barrier();
        __builtin_amdgcn_sched_barrier(0);
#pragma unroll
        for (int kk = 0; kk < 2; ++kk) {
            bf16x8 af[4], bfr[2];
#pragma unroll
            for (int i = 0; i < 4; i++)
                af[i] = *reinterpret_cast<const bf16x8*>(
                    &Ab[curA + (i * 16 + l15) * 64 + kk * 32 + l4 * 8]);
#pragma unroll
            for (int j = 0; j < 2; j++)
                bfr[j] = *reinterpret_cast<const bf16x8*>(
                    &Bb[curB + (wave * 32 + j * 16 + l15) * 64 + kk * 32 + l4 * 8]);
#pragma unroll
            for (int i = 0; i < 4; i++)
#pragma unroll
                for (int j = 0; j < 2; j++)
                    acc[i][j] = __builtin_amdgcn_mfma_f32_16x16x32_bf16(af[i], bfr[j],
                                                                        acc[i][j], 0, 0, 0);
        }
        __builtin_amdgcn_sched_barrier(0);
        __builtin_amdgcn_s_barrier();
    }

    // --- gate epilogue: C tile 64x128 f32 = 32 KB overlays the dbuf ---
    float* Cs = (float*)smem;
#pragma unroll
    for (int i = 0; i < 4; i++)
#pragma unroll
        for (int j = 0; j < 2; j++)
#pragma unroll
            for (int rr = 0; rr < 4; rr++)
                Cs[(i * 16 + l4 * 4 + rr) * 128 + (wave * 32 + j * 16 + l15)] =
                    acc[i][j][rr];
    __syncthreads();

    const int j  = tid & 31;
    const int rb = tid >> 5;          // 0..7
    const int gj = jBase + j;
    const float bi_ = bih[gj]        + bhh[gj];
    const float bf_ = bih[gj + 2048] + bhh[gj + 2048];
    const float bg_ = bih[gj + 4096] + bhh[gj + 4096];
    const float bo_ = bih[gj + 6144] + bhh[gj + 6144];
#pragma unroll
    for (int k = 0; k < 8; ++k) {
        int n = rb * 8 + k;          // 0..63
        const u16* xr = xg + (size_t)n * xg_stride;
        float gi = Cs[n * 128 + j]      + bf2f((u32)xr[gj])        + bi_;
        float gf = Cs[n * 128 + 32 + j] + bf2f((u32)xr[gj + 2048]) + bf_;
        float gg = Cs[n * 128 + 64 + j] + bf2f((u32)xr[gj + 4096]) + bg_;
        float go = Cs[n * 128 + 96 + j] + bf2f((u32)xr[gj + 6144]) + bo_;
        size_t idx = (size_t)n * 2048 + gj;
        float cc = c[idx];
        float cn = sigmf(gf) * cc + sigmf(gi) * tanhf_(gg);
        float hn = sigmf(go) * tanhf_(cn);
        c[idx] = cn;
        hbf_out[idx] = (u16)f2bfbits(hn);
        if (hf) hf[idx] = hn;
    }
}

// ---------------------------------------------------------------------------
// First LSTM step (c=0, no hW): gates from xg+bias only.
// ---------------------------------------------------------------------------
__global__ __launch_bounds__(256) void lstm_gate0(const u16* __restrict__ xg,
                                                  int xg_stride,
                                                  const float* __restrict__ bih,
                                                  const float* __restrict__ bhh,
                                                  float* __restrict__ c,
                                                  u16* __restrict__ hbf,
                                                  int rows) {
    int idx = blockIdx.x * 256 + threadIdx.x;
    int total = rows * 512;
    if (idx >= total) return;
    int n  = idx >> 9;
    int j4 = (idx & 511) * 4;

    const u16* xr = xg + (size_t)n * xg_stride + j4;
    float4 gi, gf, gg, go;
    {
        uint2 ri = *reinterpret_cast<const uint2*>(xr);
        uint2 rg = *reinterpret_cast<const uint2*>(xr + 4096);
        uint2 ro = *reinterpret_cast<const uint2*>(xr + 6144);
        gi = {bf2f(ri.x & 0xFFFFu), bf2f(ri.x >> 16), bf2f(ri.y & 0xFFFFu), bf2f(ri.y >> 16)};
        gg = {bf2f(rg.x & 0xFFFFu), bf2f(rg.x >> 16), bf2f(rg.y & 0xFFFFu), bf2f(rg.y >> 16)};
        go = {bf2f(ro.x & 0xFFFFu), bf2f(ro.x >> 16), bf2f(ro.y & 0xFFFFu), bf2f(ro.y >> 16)};
    }
    float4 bi1 = *reinterpret_cast<const float4*>(bih + j4);
    float4 bg1 = *reinterpret_cast<const float4*>(bih + 4096 + j4);
    float4 bo1 = *reinterpret_cast<const float4*>(bih + 6144 + j4);
    float4 bi2 = *reinterpret_cast<const float4*>(bhh + j4);
    float4 bg2 = *reinterpret_cast<const float4*>(bhh + 4096 + j4);
    float4 bo2 = *reinterpret_cast<const float4*>(bhh + 6144 + j4);

    gi.x += bi1.x + bi2.x; gi.y += bi1.y + bi2.y; gi.z += bi1.z + bi2.z; gi.w += bi1.w + bi2.w;
    gg.x += bg1.x + bg2.x; gg.y += bg1.y + bg2.y; gg.z += bg1.z + bg2.z; gg.w += bg1.w + bg2.w;
    go.x += bo1.x + bo2.x; go.y += bo1.y + bo2.y; go.z += bo1.z + bo2.z; go.w += bo1.w + bo2.w;

    float cx = sigmf(gi.x) * tanhf_(gg.x);
    float cy = sigmf(gi.y) * tanhf_(gg.y);
    float cz = sigmf(gi.z) * tanhf_(gg.z);
    float cw = sigmf(gi.w) * tanhf_(gg.w);
    float hx = sigmf(go.x) * tanhf_(cx);
    float hy = sigmf(go.y) * tanhf_(cy);
    float hz = sigmf(go.z) * tanhf_(cz);
    float hw_ = sigmf(go.w) * tanhf_(cw);

    float4 co = {cx, cy, cz, cw};
    *reinterpret_cast<float4*>(c + (size_t)n * 2048 + j4) = co;
    uint2 hp;
    hp.x = pack2(hx, hy);
    hp.y = pack2(hz, hw_);
    *reinterpret_cast<uint2*>(hbf + (size_t)n * 2048 + j4) = hp;
}

// ---------------------------------------------------------------------------
// Attention over 5-windows. One block per window n = b*16+t.
// ---------------------------------------------------------------------------
__global__ __launch_bounds__(256) void attn_win5(const u16* __restrict__ q0,
                                                 const u16* __restrict__ k0,
                                                 const u16* __restrict__ v0,
                                                 u16* __restrict__ att) {
    int n = blockIdx.x;  // 0..1023
    int b = n >> 4, t = n & 15;
    int tid = threadIdx.x, lane = tid & 63, wave = tid >> 6;
    int d0 = tid * 8;
    size_t base = (size_t)(b * 20 + t) * D2048;

    float qv[5][8];
#pragma unroll
    for (int i = 0; i < 5; i++) {
        uint4 v = *reinterpret_cast<const uint4*>(q0 + base + (size_t)i * D2048 + d0);
        unpack8(v, qv[i]);
    }
    float part[25];
#pragma unroll
    for (int p = 0; p < 25; p++) part[p] = 0.f;
#pragma unroll
    for (int m = 0; m < 5; m++) {
        float kv[8];
        uint4 v = *reinterpret_cast<const uint4*>(k0 + base + (size_t)m * D2048 + d0);
        unpack8(v, kv);
#pragma unroll
        for (int l = 0; l < 5; l++)
#pragma unroll
            for (int j = 0; j < 8; j++) part[l * 5 + m] += qv[l][j] * kv[j];
    }
#pragma unroll
    for (int p = 0; p < 25; p++) {
        float s = part[p];
#pragma unroll
        for (int msk = 32; msk; msk >>= 1) s += __shfl_xor(s, msk, 64);
        part[p] = s;
    }
    __shared__ float wred[4][25];
    __shared__ float wmat[25];
    if (lane == 0) {
#pragma unroll
        for (int p = 0; p < 25; p++) wred[wave][p] = part[p];
    }
    __syncthreads();
    if (tid < 5) {
        int l = tid;
        float dv[5], mx = -1e30f;
#pragma unroll
        for (int m = 0; m < 5; m++) {
            dv[m] = (wred[0][l * 5 + m] + wred[1][l * 5 + m] + wred[2][l * 5 + m] +
                     wred[3][l * 5 + m]) * SCALE;
            mx = fmaxf(mx, dv[m]);
        }
        float ssum = 0.f;
#pragma unroll
        for (int m = 0; m < 5; m++) { dv[m] = __expf(dv[m] - mx); ssum += dv[m]; }
        float inv = 1.f / ssum;
#pragma unroll
        for (int m = 0; m < 5; m++) wmat[l * 5 + m] = dv[m] * inv;
    }
    __syncthreads();

    float oacc[5][8];
#pragma unroll
    for (int l = 0; l < 5; l++)
#pragma unroll
        for (int j = 0; j < 8; j++) oacc[l][j] = 0.f;
#pragma unroll
    for (int m = 0; m < 5; m++) {
        float vv[8];
        uint4 v = *reinterpret_cast<const uint4*>(v0 + base + (size_t)m * D2048 + d0);
        unpack8(v, vv);
#pragma unroll
        for (int l = 0; l < 5; l++) {
            float w = wmat[l * 5 + m];
#pragma unroll
            for (int j = 0; j < 8; j++) oacc[l][j] += w * vv[j];
        }
    }
#pragma unroll
    for (int l = 0; l < 5; l++) {
        uint4 p;
        p.x = pack2(oacc[l][0], oacc[l][1]);
        p.y = pack2(oacc[l][2], oacc[l][3]);
        p.z = pack2(oacc[l][4], oacc[l][5]);
        p.w = pack2(oacc[l][6], oacc[l][7]);
        *reinterpret_cast<uint4*>(att + (size_t)(n * 5 + l) * D2048 + d0) = p;
    }
}

// ---------------------------------------------------------------------------
// Attention over seq-16. One block per output row r = b*16 + l.
// ---------------------------------------------------------------------------
__global__ __launch_bounds__(256) void attn_seq16(const u16* __restrict__ q2,
                                                  const u16* __restrict__ k2,
                                                  const u16* __restrict__ v2,
                                                  u16* __restrict__ att2) {
    int r = blockIdx.x;  // 0..1023
    int b = r >> 4;
    int tid = threadIdx.x, lane = tid & 63, wave = tid >> 6;
    int d0 = tid * 8;
    size_t kbase = (size_t)b * 16 * D2048;

    float qv[8];
    {
        uint4 v = *reinterpret_cast<const uint4*>(q2 + (size_t)r * D2048 + d0);
        unpack8(v, qv);
    }
    float part[16];
#pragma unroll
    for (int m = 0; m < 16; m++) part[m] = 0.f;
#pragma unroll
    for (int m = 0; m < 16; m++) {
        float kv[8];
        uint4 v = *reinterpret_cast<const uint4*>(k2 + kbase + (size_t)m * D2048 + d0);
        unpack8(v, kv);
#pragma unroll
        for (int j = 0; j < 8; j++) part[m] += qv[j] * kv[j];
    }
#pragma unroll
    for (int m = 0; m < 16; m++) {
        float s = part[m];
#pragma unroll
        for (int msk = 32; msk; msk >>= 1) s += __shfl_xor(s, msk, 64);
        part[m] = s;
    }
    __shared__ float wred[4][16];
    __shared__ float wmat[16];
    if (lane == 0) {
#pragma unroll
        for (int m = 0; m < 16; m++) wred[wave][m] = part[m];
    }
    __syncthreads();
    if (tid == 0) {
        float dv[16], mx = -1e30f;
#pragma unroll
        for (int m = 0; m < 16; m++) {
            dv[m] = (wred[0][m] + wred[1][m] + wred[2][m] + wred[3][m]) * SCALE;
            mx = fmaxf(mx, dv[m]);
        }
        float ssum = 0.f;
#pragma unroll
        for (int m = 0; m < 16; m++) { dv[m] = __expf(dv[m] - mx); ssum += dv[m]; }
        float inv = 1.f / ssum;
#pragma unroll
        for (int m = 0; m < 16; m++) wmat[m] = dv[m] * inv;
    }
    __syncthreads();

    float oacc[8];
#pragma unroll
    for (int j = 0; j < 8; j++) oacc[j] = 0.f;
#pragma unroll
    for (int m = 0; m < 16; m++) {
        float vv[8];
        uint4 v = *reinterpret_cast<const uint4*>(v2 + kbase + (size_t)m * D2048 + d0);
        unpack8(v, vv);
        float w = wmat[m];
#pragma unroll
        for (int j = 0; j < 8; j++) oacc[j] += w * vv[j];
    }
    uint4 p;
    p.x = pack2(oacc[0], oacc[1]);
    p.y = pack2(oacc[2], oacc[3]);
    p.z = pack2(oacc[4], oacc[5]);
    p.w = pack2(oacc[6], oacc[7]);
    *reinterpret_cast<uint4*>(att2 + (size_t)r * D2048 + d0) = p;
}

// ---------------------------------------------------------------------------
// LayerNorm over last dim (2048). One block per row. Writes fp32 + bf16 copy.
// ---------------------------------------------------------------------------
__global__ __launch_bounds__(256) void layernorm_k(const float* __restrict__ x,
                                                   const float* __restrict__ g,
                                                   const float* __restrict__ b,
                                                   float* __restrict__ y,
                                                   u16* __restrict__ ybf) {
    int row = blockIdx.x;
    int tid = threadIdx.x, lane = tid & 63, wave = tid >> 6;
    const float* xr = x + (size_t)row * D2048;
    int j = tid * 8;
    float4 v1 = *reinterpret_cast<const float4*>(xr + j);
    float4 v2 = *reinterpret_cast<const float4*>(xr + j + 4);
    float s  = v1.x + v1.y + v1.z + v1.w + v2.x + v2.y + v2.z + v2.w;
    float s2 = v1.x * v1.x + v1.y * v1.y + v1.z * v1.z + v1.w * v1.w +
               v2.x * v2.x + v2.y * v2.y + v2.z * v2.z + v2.w * v2.w;
#pragma unroll
    for (int msk = 32; msk; msk >>= 1) {
        s  += __shfl_xor(s, msk, 64);
        s2 += __shfl_xor(s2, msk, 64);
    }
    __shared__ float red[4][2];
    if (lane == 0) { red[wave][0] = s; red[wave][1] = s2; }
    __syncthreads();
    s  = red[0][0] + red[1][0] + red[2][0] + red[3][0];
    s2 = red[0][1] + red[1][1] + red[2][1] + red[3][1];
    float mu  = s * (1.f / 2048.f);
    float var = s2 * (1.f / 2048.f) - mu * mu;
    float rs  = __frsqrt_rn(var + 1e-5f);

    float4 g1 = *reinterpret_cast<const float4*>(g + j);
    float4 g2 = *reinterpret_cast<const float4*>(g + j + 4);
    float4 b1 = *reinterpret_cast<const float4*>(b + j);
    float4 b2 = *reinterpret_cast<const float4*>(b + j + 4);
    float o[8];
    o[0] = (v1.x - mu) * rs * g1.x + b1.x;
    o[1] = (v1.y - mu) * rs * g1.y + b1.y;
    o[2] = (v1.z - mu) * rs * g1.z + b1.z;
    o[3] = (v1.w - mu) * rs * g1.w + b1.w;
    o[4] = (v2.x - mu) * rs * g2.x + b2.x;
    o[5] = (v2.y - mu) * rs * g2.y + b2.y;
    o[6] = (v2.z - mu) * rs * g2.z + b2.z;
    o[7] = (v2.w - mu) * rs * g2.w + b2.w;
    float4 o1 = {o[0], o[1], o[2], o[3]};
    float4 o2 = {o[4], o[5], o[6], o[7]};
    float* yr = y + (size_t)row * D2048;
    *reinterpret_cast<float4*>(yr + j)     = o1;
    *reinterpret_cast<float4*>(yr + j + 4) = o2;
    uint4 p;
    p.x = pack2(o[0], o[1]);
    p.y = pack2(o[2], o[3]);
    p.z = pack2(o[4], o[5]);
    p.w = pack2(o[6], o[7]);
    *reinterpret_cast<uint4*>(ybf + (size_t)row * D2048 + j) = p;
}

// ---------------------------------------------------------------------------
static inline void launch_qkv(hipStream_t s, const u16* A, const u16* Wq,
                              const u16* Wk, const u16* Wv, const float* bq,
                              const float* bk, const float* bv, u16* out,
                              int M, int N, int K) {
    dim3 grid(N / 128, M / 128, 3);
    gemm_qkv<<<grid, 256, 0, s>>>(A, Wq, Wk, Wv, bq, bk, bv, out,
                                  (size_t)M * N, M, N, K);
}

extern "C" void kernel_launch(void* const* d_in, const int* in_sizes, int n_in,
                              void* d_out, int out_size, void* d_ws, size_t ws_size,
                              hipStream_t stream) {
    const float* fc      = (const float*)d_in[0];
    const float* nsa_Wq  = (const float*)d_in[1];
    const float* nsa_Wk  = (const float*)d_in[2];
    const float* nsa_Wv  = (const float*)d_in[3];
    const float* nsa_bq  = (const float*)d_in[4];
    const float* nsa_bk  = (const float*)d_in[5];
    const float* nsa_bv  = (const float*)d_in[6];
    const float* nsa_Wih = (const float*)d_in[7];
    const float* nsa_Whh = (const float*)d_in[8];
    const float* nsa_bih = (const float*)d_in[9];
    const float* nsa_bhh = (const float*)d_in[10];
    const float* sa_Wq   = (const float*)d_in[11];
    const float* sa_Wk   = (const float*)d_in[12];
    const float* sa_Wv   = (const float*)d_in[13];
    const float* sa_bq   = (const float*)d_in[14];
    const float* sa_bk   = (const float*)d_in[15];
    const float* sa_bv   = (const float*)d_in[16];
    const float* sa_Wih  = (const float*)d_in[17];
    const float* sa_Whh  = (const float*)d_in[18];
    const float* sa_bih  = (const float*)d_in[19];
    const float* sa_bhh  = (const float*)d_in[20];
    const float* ln_g    = (const float*)d_in[21];
    const float* ln_b    = (const float*)d_in[22];

    float* outF   = (float*)d_out;
    float* out_sa = outF;            // (64,2048)
    float* out_ln = outF + 131072;   // (64,16,2048)

    char* W = (char*)d_ws;
    u16* W_q   = (u16*)(W + 0);          // nsa->sa QKV weights; h1/c1/hbfA alias
    u16* W_k   = (u16*)(W + 8388608);
    u16* W_v   = (u16*)(W + 16777216);
    u16* W_ih  = (u16*)(W + 25165824);   // nsa_Wih -> sa_Wih
    u16* W_hh1 = (u16*)(W + 58720256);   // nsa_Whh
    u16* W_hh2 = (u16*)(W + 92274688);   // sa_Whh
    u16*   Xbf  = (u16*)(W + 125829120); // fc bf16; lnbf alias
    u16*   q0   = (u16*)(W + 131072000); // q0/k0/v0; hbfB alias; q2/k2/v2
    u16*   att1 = (u16*)(W + 146800640); // att1/att2
    u16*   xg   = (u16*)(W + 167772160); // 5120x8192 bf16 (xg2 subset)
    // aliases:
    float* h1    = (float*)(W + 0);         // 1024x2048 f32 (nsa final h, until LN)
    float* c1    = (float*)(W + 8388608);   // 1024x2048 f32
    u16*   hbfA  = (u16*)(W + 16777216);    // 1024x2048 bf16 ping
    u16*   hbfB  = (u16*)(W + 131072000);   // 1024x2048 bf16 pong (dead q0 region)
    u16*   lnbf  = Xbf;
    u16*   q2    = q0;
    u16*   att2  = att1;
    float* c2    = (float*)(W + 148373504); // 64x2048 f32 (dead att2 tail region)
    u16*   h2bfA = (u16*)(W + 148897792);   // 64x2048 bf16 ping
    u16*   h2bfB = (u16*)(W + 149422080);   // 64x2048 bf16 pong

    // 0) convert fc + nsa weights + sa_Whh to bf16
    {
        CvtArgs a{};
        a.src[0] = fc;      a.dst[0] = Xbf;   a.n4[0] = 655360;
        a.src[1] = nsa_Wq;  a.dst[1] = W_q;   a.n4[1] = 1048576;
        a.src[2] = nsa_Wk;  a.dst[2] = W_k;   a.n4[2] = 1048576;
        a.src[3] = nsa_Wv;  a.dst[3] = W_v;   a.n4[3] = 1048576;
        a.src[4] = nsa_Wih; a.dst[4] = W_ih;  a.n4[4] = 4194304;
        a.src[5] = nsa_Whh; a.dst[5] = W_hh1; a.n4[5] = 4194304;
        a.src[6] = sa_Whh;  a.dst[6] = W_hh2; a.n4[6] = 4194304;
        a.nseg = 7;
        cvt_multi<<<2048, 256, 0, stream>>>(a);
    }

    // 1) nsa QKV on the 1280 unique rows (z=3, 480 blocks)
    launch_qkv(stream, Xbf, W_q, W_k, W_v, nsa_bq, nsa_bk, nsa_bv, q0, 1280, 2048, 2048);

    // 2) windowed attention
    attn_win5<<<1024, 256, 0, stream>>>(q0, q0 + 2621440, q0 + 5242880, att1);

    // 3) xg for ALL 5 steps: one M=5120 8-phase GEMM (640 blocks), bf16 out
    gemm256<true><<<dim3(32, 20), 512, 0, stream>>>(att1, 2048, W_ih, xg,
                                                    5120, 8192, 2048);

    // 4) nsa LSTM over 5 steps; steps 1..4 = fused GEMM+gate (512 blocks)
    lstm_gate0<<<2048, 256, 0, stream>>>(xg, 40960, nsa_bih, nsa_bhh, c1, hbfA, 1024);
    {
        u16* hin = hbfA;
        for (int t = 1; t < 5; ++t) {
            u16* hout = (t & 1) ? hbfB : hbfA;
            if (t == 4)
                gemm_gate128<true><<<dim3(64, 8), 256, 0, stream>>>(
                    hin, W_hh1, xg + (size_t)t * 8192, 40960, nsa_bih, nsa_bhh,
                    c1, hout, h1, 2048);
            else
                gemm_gate128<false><<<dim3(64, 8), 256, 0, stream>>>(
                    hin, W_hh1, xg + (size_t)t * 8192, 40960, nsa_bih, nsa_bhh,
                    c1, hout, nullptr, 2048);
            hin = hout;
        }
    }

    // 5) LayerNorm -> output 1 (fp32) + bf16 copy for stage 2
    layernorm_k<<<1024, 256, 0, stream>>>(h1, ln_g, ln_b, out_ln, lnbf);

    // 5b) convert sa single-use weights into the (now dead) nsa slots
    {
        CvtArgs a{};
        a.src[0] = sa_Wq;  a.dst[0] = W_q;  a.n4[0] = 1048576;
        a.src[1] = sa_Wk;  a.dst[1] = W_k;  a.n4[1] = 1048576;
        a.src[2] = sa_Wv;  a.dst[2] = W_v;  a.n4[2] = 1048576;
        a.src[3] = sa_Wih; a.dst[3] = W_ih; a.n4[3] = 4194304;
        a.nseg = 4;
        cvt_multi<<<2048, 256, 0, stream>>>(a);
    }

    // 6) sa QKV (z=3, 384 blocks)
    launch_qkv(stream, lnbf, W_q, W_k, W_v, sa_bq, sa_bk, sa_bv, q2, 1024, 2048, 2048);

    // 7) seq-16 attention
    attn_seq16<<<1024, 256, 0, stream>>>(q2, q2 + 2097152, q2 + 4194304, att2);

    // 8) xg2 = att2 @ saWih^T (8-phase, 128 blocks, bf16 out)
    gemm256<true><<<dim3(32, 4), 512, 0, stream>>>(att2, 2048, W_ih, xg,
                                                   1024, 8192, 2048);

    // 9) sa LSTM over 16 steps; steps 1..15 = fused GEMM+gate (64 blocks)
    lstm_gate0<<<128, 256, 0, stream>>>(xg, 131072, sa_bih, sa_bhh, c2, h2bfA, 64);
    {
        u16* hin = h2bfA;
        for (int t = 1; t < 16; ++t) {
            u16* hout = (t & 1) ? h2bfB : h2bfA;
            gemm_gate64<<<dim3(64), 256, 0, stream>>>(
                hin, W_hh2, xg + (size_t)t * 8192, 131072, sa_bih, sa_bhh,
                c2, hout, (t == 15) ? out_sa : nullptr, 2048);
            hin = hout;
        }
    }
}

// Round 6
// 953.334 us; speedup vs baseline: 1.2286x; 1.2286x over previous
//
#include <hip/hip_runtime.h>
#include <hip/hip_bf16.h>

typedef unsigned int  u32;
typedef unsigned short u16;

typedef __bf16 bf16x8 __attribute__((ext_vector_type(8)));
typedef float  f32x4  __attribute__((ext_vector_type(4)));

#define D2048 2048
#define SCALE 0.022097086912079612f

__device__ __forceinline__ u32 f2bfbits(float f) {
    u32 u = __float_as_uint(f);
    return (u + 0x7FFFu + ((u >> 16) & 1u)) >> 16;   // RNE
}
__device__ __forceinline__ u32 pack2(float a, float b) {
    return f2bfbits(a) | (f2bfbits(b) << 16);
}
__device__ __forceinline__ float bf2f(u32 h) {
    return __uint_as_float(h << 16);
}
__device__ __forceinline__ void unpack8(uint4 v, float* f) {
    f[0] = bf2f(v.x & 0xFFFFu); f[1] = bf2f(v.x >> 16);
    f[2] = bf2f(v.y & 0xFFFFu); f[3] = bf2f(v.y >> 16);
    f[4] = bf2f(v.z & 0xFFFFu); f[5] = bf2f(v.z >> 16);
    f[6] = bf2f(v.w & 0xFFFFu); f[7] = bf2f(v.w >> 16);
}
__device__ __forceinline__ float sigmf(float x) { return 1.f / (1.f + __expf(-x)); }
__device__ __forceinline__ float tanhf_(float x) {
    x = fminf(15.f, fmaxf(-15.f, x));
    float e = __expf(2.f * x);
    return (e - 1.f) / (e + 1.f);
}

// async global->LDS, 16B per lane. LDS dest: wave-uniform base + lane*16B.
__device__ __forceinline__ void gload_lds16(const u16* g, u16* l) {
    __builtin_amdgcn_global_load_lds(
        (const __attribute__((address_space(1))) unsigned int*)g,
        (__attribute__((address_space(3))) unsigned int*)l,
        16, 0, 0);
}

// ---------------------------------------------------------------------------
// Multi-segment fp32 -> bf16 conversion (grid-stride per segment)
// ---------------------------------------------------------------------------
struct CvtArgs {
    const float* src[8];
    u16*         dst[8];
    int          n4[8];
    int          nseg;
};
__global__ __launch_bounds__(256) void cvt_multi(CvtArgs a) {
    int stride = gridDim.x * 256;
    for (int s = 0; s < a.nseg; ++s) {
        const float4* S = reinterpret_cast<const float4*>(a.src[s]);
        uint2*        D = reinterpret_cast<uint2*>(a.dst[s]);
        int n4 = a.n4[s];
        for (int i = blockIdx.x * 256 + threadIdx.x; i < n4; i += stride) {
            float4 v = S[i];
            uint2 p;
            p.x = pack2(v.x, v.y);
            p.y = pack2(v.z, v.w);
            D[i] = p;
        }
    }
}

// ---------------------------------------------------------------------------
// 256x256 8-phase GEMM (bank-conflict-free XOR swizzle, counted vmcnt).
// C[M][N] = A[M][K](bf16, stride lda) * B[N][K](bf16)^T, bf16 or f32 out.
// ---------------------------------------------------------------------------
template <bool OUT_BF16>
__global__ __launch_bounds__(512, 2) void gemm256(const u16* __restrict__ A, int lda,
                                                  const u16* __restrict__ B,
                                                  void* __restrict__ C0,
                                                  int M, int N, int K) {
    __shared__ u16 Ab[2][16384];
    __shared__ u16 Bb[2][16384];

    const int tid  = threadIdx.x;
    const int lane = tid & 63;
    const int wid  = tid >> 6;       // 0..7
    const int wm   = wid >> 2;       // 0..1
    const int wn   = wid & 3;        // 0..3
    const int l15  = lane & 15, l4 = lane >> 4;
    const int rowBase = blockIdx.y * 256;
    const int colBase = blockIdx.x * 256;

    // staging source (pre-swizzled: LDS chunk c' holds global chunk c'^(row&7))
    const int srow8 = lane >> 3;                   // row-within-8 (== row&7)
    const int scw   = ((lane & 7) ^ srow8) * 8;    // swizzled 16B chunk -> elems
    const u16* gA = A + (size_t)(rowBase + wid * 8 + srow8) * lda + scw;
    const u16* gB = B + (size_t)(colBase + wid * 8 + srow8) * (size_t)K + scw;
    const int ldsW = wid * 512;                    // wave base within 64-row chunk

#define STAGE_A(buf, koff, q) \
    gload_lds16(gA + (size_t)((q) * 64) * lda + (koff), &Ab[buf][(q) * 4096 + ldsW])
#define STAGE_B(buf, koff, q) \
    gload_lds16(gB + (size_t)((q) * 64) * (size_t)K + (koff), &Bb[buf][(q) * 4096 + ldsW])

    f32x4 acc[8][4];
#pragma unroll
    for (int m = 0; m < 8; m++)
#pragma unroll
        for (int n = 0; n < 4; n++) acc[m][n] = f32x4{0.f, 0.f, 0.f, 0.f};

    const int nt = K >> 6;

#pragma unroll
    for (int q = 0; q < 4; ++q) { STAGE_A(0, 0, q); STAGE_B(0, 0, q); }

    const int swzA = (l15 & 7);  // row&7 for all frag rows (row ≡ l15 mod 16)

    for (int t = 0; t < nt; ++t) {
        const int cur = t & 1;
        const int nxt = cur ^ 1;
        const int kN  = (t + 1) << 6;
        const bool more = (t + 1 < nt);

        if (more) {
            STAGE_A(nxt, kN, 0);
            STAGE_A(nxt, kN, 1);
            asm volatile("s_waitcnt vmcnt(2)" ::: "memory");
        } else {
            asm volatile("s_waitcnt vmcnt(0)" ::: "memory");
        }
        __builtin_amdgcn_s_barrier();

        bf16x8 bfrag[4][2];
#pragma unroll
        for (int n = 0; n < 4; ++n)
#pragma unroll
            for (int kk = 0; kk < 2; ++kk)
                bfrag[n][kk] = *reinterpret_cast<const bf16x8*>(
                    &Bb[cur][(wn * 64 + n * 16 + l15) * 64 +
                             (((kk * 4 + l4) ^ swzA) * 8)]);

#pragma unroll
        for (int p = 0; p < 4; ++p) {
            bf16x8 afr[2][2];
#pragma unroll
            for (int mi = 0; mi < 2; ++mi)
#pragma unroll
                for (int kk = 0; kk < 2; ++kk)
                    afr[mi][kk] = *reinterpret_cast<const bf16x8*>(
                        &Ab[cur][(wm * 128 + (p * 2 + mi) * 16 + l15) * 64 +
                                 (((kk * 4 + l4) ^ swzA) * 8)]);
            if (more) {
                if (p == 0)      { STAGE_A(nxt, kN, 2); STAGE_A(nxt, kN, 3); }
                else if (p == 1) { STAGE_B(nxt, kN, 0); STAGE_B(nxt, kN, 1); }
                else if (p == 2) { STAGE_B(nxt, kN, 2); STAGE_B(nxt, kN, 3); }
            }
            __builtin_amdgcn_s_barrier();
            __builtin_amdgcn_sched_barrier(0);
            __builtin_amdgcn_s_setprio(1);
#pragma unroll
            for (int kk = 0; kk < 2; ++kk)
#pragma unroll
                for (int mi = 0; mi < 2; ++mi)
#pragma unroll
                    for (int n = 0; n < 4; ++n)
                        acc[p * 2 + mi][n] = __builtin_amdgcn_mfma_f32_16x16x32_bf16(
                            afr[mi][kk], bfrag[n][kk], acc[p * 2 + mi][n], 0, 0, 0);
            __builtin_amdgcn_s_setprio(0);
            __builtin_amdgcn_sched_barrier(0);
            __builtin_amdgcn_s_barrier();
        }
    }
#undef STAGE_A
#undef STAGE_B

#pragma unroll
    for (int m = 0; m < 8; ++m) {
        int row0 = rowBase + wm * 128 + m * 16 + l4 * 4;
#pragma unroll
        for (int n = 0; n < 4; ++n) {
            int col = colBase + wn * 64 + n * 16 + l15;
#pragma unroll
            for (int rr = 0; rr < 4; ++rr) {
                if (OUT_BF16)
                    ((u16*)C0)[(size_t)(row0 + rr) * N + col] = (u16)f2bfbits(acc[m][n][rr]);
                else
                    ((float*)C0)[(size_t)(row0 + rr) * N + col] = acc[m][n][rr];
            }
        }
    }
}

// ---------------------------------------------------------------------------
// QKV GEMM: 128x128 tile, BK=64, 4 waves, 2-phase dbuf, grid.z selects panel.
// ---------------------------------------------------------------------------
__global__ __launch_bounds__(256) void gemm_qkv(const u16* __restrict__ A,
                                                const u16* __restrict__ B0,
                                                const u16* __restrict__ B1,
                                                const u16* __restrict__ B2,
                                                const float* __restrict__ bias0,
                                                const float* __restrict__ bias1,
                                                const float* __restrict__ bias2,
                                                u16* __restrict__ Cout,
                                                size_t zCstride,
                                                int M, int N, int K) {
    __shared__ u16 Abuf[2][128 * 64];
    __shared__ u16 Bbuf[2][128 * 64];

    const int tid  = threadIdx.x;
    const int lane = tid & 63;
    const int wave = tid >> 6;
    const int wr   = (wave >> 1) * 64;
    const int wc   = (wave & 1) * 64;
    const int rowBase = blockIdx.y * 128;
    const int colBase = blockIdx.x * 128;
    const int l15 = lane & 15, l4 = lane >> 4;
    const int srow = lane >> 3;
    const int scol = (lane & 7) * 8;

    const int z = blockIdx.z;
    const u16* B      = (z == 0) ? B0 : ((z == 1) ? B1 : B2);
    const float* bias = (z == 0) ? bias0 : ((z == 1) ? bias1 : bias2);
    u16* C = Cout + (size_t)z * zCstride;

    const u16* ga = A + (size_t)(rowBase + wave * 32 + srow) * K + scol;
    const u16* gb = B + (size_t)(colBase + wave * 32 + srow) * K + scol;
    const int ldsOff = (wave * 32) * 64;

    f32x4 acc[4][4];
#pragma unroll
    for (int i = 0; i < 4; i++)
#pragma unroll
        for (int j = 0; j < 4; j++) acc[i][j] = f32x4{0.f, 0.f, 0.f, 0.f};

    const int nt = K >> 6;

#pragma unroll
    for (int i = 0; i < 4; ++i) {
        gload_lds16(ga + (size_t)(i * 8) * K, &Abuf[0][ldsOff + i * 8 * 64]);
        gload_lds16(gb + (size_t)(i * 8) * K, &Bbuf[0][ldsOff + i * 8 * 64]);
    }

    for (int t = 0; t < nt; ++t) {
        const int cur = t & 1;
        if (t + 1 < nt) {
            const int k1 = (t + 1) << 6;
#pragma unroll
            for (int i = 0; i < 4; ++i) {
                gload_lds16(ga + (size_t)(i * 8) * K + k1,
                            &Abuf[cur ^ 1][ldsOff + i * 8 * 64]);
                gload_lds16(gb + (size_t)(i * 8) * K + k1,
                            &Bbuf[cur ^ 1][ldsOff + i * 8 * 64]);
            }
            asm volatile("s_waitcnt vmcnt(8)" ::: "memory");
        } else {
            asm volatile("s_waitcnt vmcnt(0)" ::: "memory");
        }
        __builtin_amdgcn_s_barrier();
        __builtin_amdgcn_sched_barrier(0);
#pragma unroll
        for (int kk = 0; kk < 2; ++kk) {
            bf16x8 af[4], bfr[4];
#pragma unroll
            for (int i = 0; i < 4; i++) {
                af[i]  = *reinterpret_cast<const bf16x8*>(
                    &Abuf[cur][(wr + i * 16 + l15) * 64 + kk * 32 + l4 * 8]);
                bfr[i] = *reinterpret_cast<const bf16x8*>(
                    &Bbuf[cur][(wc + i * 16 + l15) * 64 + kk * 32 + l4 * 8]);
            }
#pragma unroll
            for (int i = 0; i < 4; i++)
#pragma unroll
                for (int j = 0; j < 4; j++)
                    acc[i][j] = __builtin_amdgcn_mfma_f32_16x16x32_bf16(af[i], bfr[j],
                                                                        acc[i][j], 0, 0, 0);
        }
        __builtin_amdgcn_sched_barrier(0);
        __builtin_amdgcn_s_barrier();
    }

#pragma unroll
    for (int i = 0; i < 4; i++) {
        int row0 = rowBase + wr + i * 16 + l4 * 4;
#pragma unroll
        for (int j = 0; j < 4; j++) {
            int col = colBase + wc + j * 16 + l15;
            float bv = bias[col];
#pragma unroll
            for (int rr = 0; rr < 4; rr++)
                C[(size_t)(row0 + rr) * N + col] = (u16)f2bfbits(acc[i][j][rr] + bv);
        }
    }
}

// ---------------------------------------------------------------------------
// Plain 128x128 GEMM, bf16 out, no bias (for xg2: M=1024 -> 512 blocks).
// ---------------------------------------------------------------------------
__global__ __launch_bounds__(256) void gemm128_bf(const u16* __restrict__ A,
                                                  const u16* __restrict__ B,
                                                  u16* __restrict__ C,
                                                  int M, int N, int K) {
    __shared__ u16 Abuf[2][128 * 64];
    __shared__ u16 Bbuf[2][128 * 64];

    const int tid  = threadIdx.x;
    const int lane = tid & 63;
    const int wave = tid >> 6;
    const int wr   = (wave >> 1) * 64;
    const int wc   = (wave & 1) * 64;
    const int rowBase = blockIdx.y * 128;
    const int colBase = blockIdx.x * 128;
    const int l15 = lane & 15, l4 = lane >> 4;
    const int srow = lane >> 3;
    const int scol = (lane & 7) * 8;

    const u16* ga = A + (size_t)(rowBase + wave * 32 + srow) * K + scol;
    const u16* gb = B + (size_t)(colBase + wave * 32 + srow) * K + scol;
    const int ldsOff = (wave * 32) * 64;

    f32x4 acc[4][4];
#pragma unroll
    for (int i = 0; i < 4; i++)
#pragma unroll
        for (int j = 0; j < 4; j++) acc[i][j] = f32x4{0.f, 0.f, 0.f, 0.f};

    const int nt = K >> 6;

#pragma unroll
    for (int i = 0; i < 4; ++i) {
        gload_lds16(ga + (size_t)(i * 8) * K, &Abuf[0][ldsOff + i * 8 * 64]);
        gload_lds16(gb + (size_t)(i * 8) * K, &Bbuf[0][ldsOff + i * 8 * 64]);
    }

    for (int t = 0; t < nt; ++t) {
        const int cur = t & 1;
        if (t + 1 < nt) {
            const int k1 = (t + 1) << 6;
#pragma unroll
            for (int i = 0; i < 4; ++i) {
                gload_lds16(ga + (size_t)(i * 8) * K + k1,
                            &Abuf[cur ^ 1][ldsOff + i * 8 * 64]);
                gload_lds16(gb + (size_t)(i * 8) * K + k1,
                            &Bbuf[cur ^ 1][ldsOff + i * 8 * 64]);
            }
            asm volatile("s_waitcnt vmcnt(8)" ::: "memory");
        } else {
            asm volatile("s_waitcnt vmcnt(0)" ::: "memory");
        }
        __builtin_amdgcn_s_barrier();
        __builtin_amdgcn_sched_barrier(0);
#pragma unroll
        for (int kk = 0; kk < 2; ++kk) {
            bf16x8 af[4], bfr[4];
#pragma unroll
            for (int i = 0; i < 4; i++) {
                af[i]  = *reinterpret_cast<const bf16x8*>(
                    &Abuf[cur][(wr + i * 16 + l15) * 64 + kk * 32 + l4 * 8]);
                bfr[i] = *reinterpret_cast<const bf16x8*>(
                    &Bbuf[cur][(wc + i * 16 + l15) * 64 + kk * 32 + l4 * 8]);
            }
#pragma unroll
            for (int i = 0; i < 4; i++)
#pragma unroll
                for (int j = 0; j < 4; j++)
                    acc[i][j] = __builtin_amdgcn_mfma_f32_16x16x32_bf16(af[i], bfr[j],
                                                                        acc[i][j], 0, 0, 0);
        }
        __builtin_amdgcn_sched_barrier(0);
        __builtin_amdgcn_s_barrier();
    }

#pragma unroll
    for (int i = 0; i < 4; i++) {
        int row0 = rowBase + wr + i * 16 + l4 * 4;
#pragma unroll
        for (int j = 0; j < 4; j++) {
            int col = colBase + wc + j * 16 + l15;
#pragma unroll
            for (int rr = 0; rr < 4; rr++)
                C[(size_t)(row0 + rr) * N + col] = (u16)f2bfbits(acc[i][j][rr]);
        }
    }
}

// ---------------------------------------------------------------------------
// Fused recurrent GEMM + LSTM gate, 128-row tile (nsa loop).
// Block (jb, rb): rows rb*128 (windows), 32 hidden-j x 4 gates (128 cols).
// B rows gathered: localcol c -> Whh row jb*32 + (c&31) + (c>>5)*2048.
// ---------------------------------------------------------------------------
template <bool LAST>
__global__ __launch_bounds__(256) void gemm_gate128(
    const u16* __restrict__ A,      // h_{t-1} bf16 [M][2048]
    const u16* __restrict__ B,      // Whh bf16 [8192][2048]
    const u16* __restrict__ xg,     // xg base for this step; row stride xg_stride
    int xg_stride,
    const float* __restrict__ bih,
    const float* __restrict__ bhh,
    float* __restrict__ c,          // [M][2048] f32, read+write
    u16* __restrict__ hbf_out,      // [M][2048] bf16 (next-step A)
    float* __restrict__ hf,         // f32 h (only when LAST)
    int K) {
    __shared__ u16 smem[32768];     // 64 KB: A dbuf 32KB | B dbuf 32KB; C alias
    u16* Ab = smem;                 // [2][128*64]
    u16* Bb = smem + 16384;

    const int tid = threadIdx.x, lane = tid & 63, wave = tid >> 6;
    const int wr = (wave >> 1) * 64, wc = (wave & 1) * 64;
    const int l15 = lane & 15, l4 = lane >> 4;
    const int srow = lane >> 3, scol = (lane & 7) * 8;
    const int jBase = blockIdx.x * 32;
    const int rowBase = blockIdx.y * 128;

    const u16* ga = A + (size_t)(rowBase + wave * 32 + srow) * K + scol;
    const u16* gb[4];
#pragma unroll
    for (int i = 0; i < 4; ++i) {
        int lc = wave * 32 + i * 8 + srow;
        int br = jBase + (lc & 31) + (lc >> 5) * 2048;
        gb[i] = B + (size_t)br * K + scol;
    }
    const int ldsOff = (wave * 32) * 64;

    f32x4 acc[4][4];
#pragma unroll
    for (int i = 0; i < 4; i++)
#pragma unroll
        for (int j = 0; j < 4; j++) acc[i][j] = f32x4{0.f, 0.f, 0.f, 0.f};

    const int nt = K >> 6;
#pragma unroll
    for (int i = 0; i < 4; ++i) {
        gload_lds16(ga + (size_t)(i * 8) * K, &Ab[ldsOff + i * 8 * 64]);
        gload_lds16(gb[i], &Bb[ldsOff + i * 8 * 64]);
    }

    for (int t = 0; t < nt; ++t) {
        const int cur = (t & 1) * 8192;
        if (t + 1 < nt) {
            const int k1 = (t + 1) << 6;
            const int nxt = ((t + 1) & 1) * 8192;
#pragma unroll
            for (int i = 0; i < 4; ++i) {
                gload_lds16(ga + (size_t)(i * 8) * K + k1, &Ab[nxt + ldsOff + i * 8 * 64]);
                gload_lds16(gb[i] + k1, &Bb[nxt + ldsOff + i * 8 * 64]);
            }
            asm volatile("s_waitcnt vmcnt(8)" ::: "memory");
        } else {
            asm volatile("s_waitcnt vmcnt(0)" ::: "memory");
        }
        __builtin_amdgcn_s_barrier();
        __builtin_amdgcn_sched_barrier(0);
#pragma unroll
        for (int kk = 0; kk < 2; ++kk) {
            bf16x8 af[4], bfr[4];
#pragma unroll
            for (int i = 0; i < 4; i++) {
                af[i]  = *reinterpret_cast<const bf16x8*>(
                    &Ab[cur + (wr + i * 16 + l15) * 64 + kk * 32 + l4 * 8]);
                bfr[i] = *reinterpret_cast<const bf16x8*>(
                    &Bb[cur + (wc + i * 16 + l15) * 64 + kk * 32 + l4 * 8]);
            }
#pragma unroll
            for (int i = 0; i < 4; i++)
#pragma unroll
                for (int j = 0; j < 4; j++)
                    acc[i][j] = __builtin_amdgcn_mfma_f32_16x16x32_bf16(af[i], bfr[j],
                                                                        acc[i][j], 0, 0, 0);
        }
        __builtin_amdgcn_sched_barrier(0);
        __builtin_amdgcn_s_barrier();
    }

    // --- gate epilogue: C tile (128x128 f32 = 64 KB) overlays the dbuf ---
    float* Cs = (float*)smem;
#pragma unroll
    for (int i = 0; i < 4; i++)
#pragma unroll
        for (int j = 0; j < 4; j++)
#pragma unroll
            for (int rr = 0; rr < 4; rr++)
                Cs[(wr + i * 16 + l4 * 4 + rr) * 128 + (wc + j * 16 + l15)] =
                    acc[i][j][rr];
    __syncthreads();

    const int j  = tid & 31;
    const int rb = tid >> 5;          // 0..7
    const int gj = jBase + j;
    const float bi_ = bih[gj]        + bhh[gj];
    const float bf_ = bih[gj + 2048] + bhh[gj + 2048];
    const float bg_ = bih[gj + 4096] + bhh[gj + 4096];
    const float bo_ = bih[gj + 6144] + bhh[gj + 6144];
#pragma unroll
    for (int k = 0; k < 16; ++k) {
        int r = rb * 16 + k;
        int n = rowBase + r;
        const u16* xr = xg + (size_t)n * xg_stride;
        float gi = Cs[r * 128 + j]      + bf2f((u32)xr[gj])        + bi_;
        float gf = Cs[r * 128 + 32 + j] + bf2f((u32)xr[gj + 2048]) + bf_;
        float gg = Cs[r * 128 + 64 + j] + bf2f((u32)xr[gj + 4096]) + bg_;
        float go = Cs[r * 128 + 96 + j] + bf2f((u32)xr[gj + 6144]) + bo_;
        size_t idx = (size_t)n * 2048 + gj;
        float cc = c[idx];
        float cn = sigmf(gf) * cc + sigmf(gi) * tanhf_(gg);
        float hn = sigmf(go) * tanhf_(cn);
        c[idx] = cn;
        hbf_out[idx] = (u16)f2bfbits(hn);
        if (LAST) hf[idx] = hn;
    }
}

// ---------------------------------------------------------------------------
// Fused recurrent GEMM + gate for the sa loop, v2: 256 blocks.
// Block jb owns 8 hidden units (32 gate-cols: c = g*8+j' -> Whh row
// jb*8 + j' + g*2048). 4 waves partition the 64 batch rows (16 each, full K).
// 2-phase dbuf, 3 gload/wave/K-tile, counted vmcnt(3). Gate math in-kernel.
// ---------------------------------------------------------------------------
__global__ __launch_bounds__(256) void gemm_gate64v2(
    const u16* __restrict__ A,      // h_{t-1} bf16 [64][2048]
    const u16* __restrict__ B,      // Whh bf16 [8192][2048]
    const u16* __restrict__ xg,     // xg base for this step; row stride xg_stride
    int xg_stride,
    const float* __restrict__ bih,
    const float* __restrict__ bhh,
    float* __restrict__ c,          // [64][2048] f32
    u16* __restrict__ hbf_out,      // [64][2048] bf16
    float* __restrict__ hf,         // optional f32 h (final step) or null
    int K) {
    __shared__ u16 smem[12288];     // 24 KB: Ab [2][64*64] | Bb [2][32*64]
    u16* Ab = smem;
    u16* Bb = smem + 8192;

    const int tid = threadIdx.x, lane = tid & 63, wave = tid >> 6;
    const int l15 = lane & 15, l4 = lane >> 4;
    const int srow = lane >> 3, scol = (lane & 7) * 8;
    const int jb = blockIdx.x;      // 0..255; hidden units jb*8..+7

    const u16* ga = A + (size_t)(wave * 16 + srow) * K + scol;
    // wave w stages B rows for gate w: global row jb*8 + srow + w*2048
    const u16* gb = B + (size_t)(jb * 8 + srow + wave * 2048) * K + scol;
    const int aOff = (wave * 16) * 64;
    const int bOff = (wave * 8) * 64;

    f32x4 acc0 = f32x4{0.f, 0.f, 0.f, 0.f};
    f32x4 acc1 = f32x4{0.f, 0.f, 0.f, 0.f};

    const int nt = K >> 6;
    gload_lds16(ga,                 &Ab[aOff]);
    gload_lds16(ga + (size_t)8 * K, &Ab[aOff + 512]);
    gload_lds16(gb,                 &Bb[bOff]);

    for (int t = 0; t < nt; ++t) {
        const int curA = (t & 1) * 4096;
        const int curB = (t & 1) * 2048;
        if (t + 1 < nt) {
            const int k1 = (t + 1) << 6;
            const int nxA = ((t + 1) & 1) * 4096;
            const int nxB = ((t + 1) & 1) * 2048;
            gload_lds16(ga + k1,                 &Ab[nxA + aOff]);
            gload_lds16(ga + (size_t)8 * K + k1, &Ab[nxA + aOff + 512]);
            gload_lds16(gb + k1,                 &Bb[nxB + bOff]);
            asm volatile("s_waitcnt vmcnt(3)" ::: "memory");
        } else {
            asm volatile("s_waitcnt vmcnt(0)" ::: "memory");
        }
        __builtin_amdgcn_s_barrier();
        __builtin_amdgcn_sched_barrier(0);
#pragma unroll
        for (int kk = 0; kk < 2; ++kk) {
            bf16x8 af = *reinterpret_cast<const bf16x8*>(
                &Ab[curA + (wave * 16 + l15) * 64 + kk * 32 + l4 * 8]);
            bf16x8 b0 = *reinterpret_cast<const bf16x8*>(
                &Bb[curB + (l15) * 64 + kk * 32 + l4 * 8]);
            bf16x8 b1 = *reinterpret_cast<const bf16x8*>(
                &Bb[curB + (16 + l15) * 64 + kk * 32 + l4 * 8]);
            acc0 = __builtin_amdgcn_mfma_f32_16x16x32_bf16(af, b0, acc0, 0, 0, 0);
            acc1 = __builtin_amdgcn_mfma_f32_16x16x32_bf16(af, b1, acc1, 0, 0, 0);
        }
        __builtin_amdgcn_sched_barrier(0);
        __builtin_amdgcn_s_barrier();
    }

    // --- gate epilogue: C tile 64x32 f32 = 8 KB overlays the dbuf ---
    float* Cs = (float*)smem;
    {
        int row0 = wave * 16 + l4 * 4;
#pragma unroll
        for (int rr = 0; rr < 4; ++rr) {
            Cs[(row0 + rr) * 32 + l15]      = acc0[rr];
            Cs[(row0 + rr) * 32 + 16 + l15] = acc1[rr];
        }
    }
    __syncthreads();

    const int j  = tid & 7;
    const int gj = jb * 8 + j;
    const float bi_ = bih[gj]        + bhh[gj];
    const float bf_ = bih[gj + 2048] + bhh[gj + 2048];
    const float bg_ = bih[gj + 4096] + bhh[gj + 4096];
    const float bo_ = bih[gj + 6144] + bhh[gj + 6144];
#pragma unroll
    for (int k = 0; k < 2; ++k) {
        int row = (tid >> 3) + k * 32;   // 0..63
        const u16* xr = xg + (size_t)row * xg_stride;
        float gi = Cs[row * 32 + j]      + bf2f((u32)xr[gj])        + bi_;
        float gf = Cs[row * 32 + 8 + j]  + bf2f((u32)xr[gj + 2048]) + bf_;
        float gg = Cs[row * 32 + 16 + j] + bf2f((u32)xr[gj + 4096]) + bg_;
        float go = Cs[row * 32 + 24 + j] + bf2f((u32)xr[gj + 6144]) + bo_;
        size_t idx = (size_t)row * 2048 + gj;
        float cc = c[idx];
        float cn = sigmf(gf) * cc + sigmf(gi) * tanhf_(gg);
        float hn = sigmf(go) * tanhf_(cn);
        c[idx] = cn;
        hbf_out[idx] = (u16)f2bfbits(hn);
        if (hf) hf[idx] = hn;
    }
}

// ---------------------------------------------------------------------------
// First LSTM step (c=0, no hW): gates from xg+bias only.
// ---------------------------------------------------------------------------
__global__ __launch_bounds__(256) void lstm_gate0(const u16* __restrict__ xg,
                                                  int xg_stride,
                                                  const float* __restrict__ bih,
                                                  const float* __restrict__ bhh,
                                                  float* __restrict__ c,
                                                  u16* __restrict__ hbf,
                                                  int rows) {
    int idx = blockIdx.x * 256 + threadIdx.x;
    int total = rows * 512;
    if (idx >= total) return;
    int n  = idx >> 9;
    int j4 = (idx & 511) * 4;

    const u16* xr = xg + (size_t)n * xg_stride + j4;
    float4 gi, gg, go;
    {
        uint2 ri = *reinterpret_cast<const uint2*>(xr);
        uint2 rg = *reinterpret_cast<const uint2*>(xr + 4096);
        uint2 ro = *reinterpret_cast<const uint2*>(xr + 6144);
        gi = {bf2f(ri.x & 0xFFFFu), bf2f(ri.x >> 16), bf2f(ri.y & 0xFFFFu), bf2f(ri.y >> 16)};
        gg = {bf2f(rg.x & 0xFFFFu), bf2f(rg.x >> 16), bf2f(rg.y & 0xFFFFu), bf2f(rg.y >> 16)};
        go = {bf2f(ro.x & 0xFFFFu), bf2f(ro.x >> 16), bf2f(ro.y & 0xFFFFu), bf2f(ro.y >> 16)};
    }
    float4 bi1 = *reinterpret_cast<const float4*>(bih + j4);
    float4 bg1 = *reinterpret_cast<const float4*>(bih + 4096 + j4);
    float4 bo1 = *reinterpret_cast<const float4*>(bih + 6144 + j4);
    float4 bi2 = *reinterpret_cast<const float4*>(bhh + j4);
    float4 bg2 = *reinterpret_cast<const float4*>(bhh + 4096 + j4);
    float4 bo2 = *reinterpret_cast<const float4*>(bhh + 6144 + j4);

    gi.x += bi1.x + bi2.x; gi.y += bi1.y + bi2.y; gi.z += bi1.z + bi2.z; gi.w += bi1.w + bi2.w;
    gg.x += bg1.x + bg2.x; gg.y += bg1.y + bg2.y; gg.z += bg1.z + bg2.z; gg.w += bg1.w + bg2.w;
    go.x += bo1.x + bo2.x; go.y += bo1.y + bo2.y; go.z += bo1.z + bo2.z; go.w += bo1.w + bo2.w;

    float cx = sigmf(gi.x) * tanhf_(gg.x);
    float cy = sigmf(gi.y) * tanhf_(gg.y);
    float cz = sigmf(gi.z) * tanhf_(gg.z);
    float cw = sigmf(gi.w) * tanhf_(gg.w);
    float hx = sigmf(go.x) * tanhf_(cx);
    float hy = sigmf(go.y) * tanhf_(cy);
    float hz = sigmf(go.z) * tanhf_(cz);
    float hw_ = sigmf(go.w) * tanhf_(cw);

    float4 co = {cx, cy, cz, cw};
    *reinterpret_cast<float4*>(c + (size_t)n * 2048 + j4) = co;
    uint2 hp;
    hp.x = pack2(hx, hy);
    hp.y = pack2(hz, hw_);
    *reinterpret_cast<uint2*>(hbf + (size_t)n * 2048 + j4) = hp;
}

// ---------------------------------------------------------------------------
// Attention over 5-windows. One block per window n = b*16+t.
// ---------------------------------------------------------------------------
__global__ __launch_bounds__(256) void attn_win5(const u16* __restrict__ q0,
                                                 const u16* __restrict__ k0,
                                                 const u16* __restrict__ v0,
                                                 u16* __restrict__ att) {
    int n = blockIdx.x;  // 0..1023
    int b = n >> 4, t = n & 15;
    int tid = threadIdx.x, lane = tid & 63, wave = tid >> 6;
    int d0 = tid * 8;
    size_t base = (size_t)(b * 20 + t) * D2048;

    float qv[5][8];
#pragma unroll
    for (int i = 0; i < 5; i++) {
        uint4 v = *reinterpret_cast<const uint4*>(q0 + base + (size_t)i * D2048 + d0);
        unpack8(v, qv[i]);
    }
    float part[25];
#pragma unroll
    for (int p = 0; p < 25; p++) part[p] = 0.f;
#pragma unroll
    for (int m = 0; m < 5; m++) {
        float kv[8];
        uint4 v = *reinterpret_cast<const uint4*>(k0 + base + (size_t)m * D2048 + d0);
        unpack8(v, kv);
#pragma unroll
        for (int l = 0; l < 5; l++)
#pragma unroll
            for (int j = 0; j < 8; j++) part[l * 5 + m] += qv[l][j] * kv[j];
    }
#pragma unroll
    for (int p = 0; p < 25; p++) {
        float s = part[p];
#pragma unroll
        for (int msk = 32; msk; msk >>= 1) s += __shfl_xor(s, msk, 64);
        part[p] = s;
    }
    __shared__ float wred[4][25];
    __shared__ float wmat[25];
    if (lane == 0) {
#pragma unroll
        for (int p = 0; p < 25; p++) wred[wave][p] = part[p];
    }
    __syncthreads();
    if (tid < 5) {
        int l = tid;
        float dv[5], mx = -1e30f;
#pragma unroll
        for (int m = 0; m < 5; m++) {
            dv[m] = (wred[0][l * 5 + m] + wred[1][l * 5 + m] + wred[2][l * 5 + m] +
                     wred[3][l * 5 + m]) * SCALE;
            mx = fmaxf(mx, dv[m]);
        }
        float ssum = 0.f;
#pragma unroll
        for (int m = 0; m < 5; m++) { dv[m] = __expf(dv[m] - mx); ssum += dv[m]; }
        float inv = 1.f / ssum;
#pragma unroll
        for (int m = 0; m < 5; m++) wmat[l * 5 + m] = dv[m] * inv;
    }
    __syncthreads();

    float oacc[5][8];
#pragma unroll
    for (int l = 0; l < 5; l++)
#pragma unroll
        for (int j = 0; j < 8; j++) oacc[l][j] = 0.f;
#pragma unroll
    for (int m = 0; m < 5; m++) {
        float vv[8];
        uint4 v = *reinterpret_cast<const uint4*>(v0 + base + (size_t)m * D2048 + d0);
        unpack8(v, vv);
#pragma unroll
        for (int l = 0; l < 5; l++) {
            float w = wmat[l * 5 + m];
#pragma unroll
            for (int j = 0; j < 8; j++) oacc[l][j] += w * vv[j];
        }
    }
#pragma unroll
    for (int l = 0; l < 5; l++) {
        uint4 p;
        p.x = pack2(oacc[l][0], oacc[l][1]);
        p.y = pack2(oacc[l][2], oacc[l][3]);
        p.z = pack2(oacc[l][4], oacc[l][5]);
        p.w = pack2(oacc[l][6], oacc[l][7]);
        *reinterpret_cast<uint4*>(att + (size_t)(n * 5 + l) * D2048 + d0) = p;
    }
}

// ---------------------------------------------------------------------------
// Attention over seq-16. One block per output row r = b*16 + l.
// ---------------------------------------------------------------------------
__global__ __launch_bounds__(256) void attn_seq16(const u16* __restrict__ q2,
                                                  const u16* __restrict__ k2,
                                                  const u16* __restrict__ v2,
                                                  u16* __restrict__ att2) {
    int r = blockIdx.x;  // 0..1023
    int b = r >> 4;
    int tid = threadIdx.x, lane = tid & 63, wave = tid >> 6;
    int d0 = tid * 8;
    size_t kbase = (size_t)b * 16 * D2048;

    float qv[8];
    {
        uint4 v = *reinterpret_cast<const uint4*>(q2 + (size_t)r * D2048 + d0);
        unpack8(v, qv);
    }
    float part[16];
#pragma unroll
    for (int m = 0; m < 16; m++) part[m] = 0.f;
#pragma unroll
    for (int m = 0; m < 16; m++) {
        float kv[8];
        uint4 v = *reinterpret_cast<const uint4*>(k2 + kbase + (size_t)m * D2048 + d0);
        unpack8(v, kv);
#pragma unroll
        for (int j = 0; j < 8; j++) part[m] += qv[j] * kv[j];
    }
#pragma unroll
    for (int m = 0; m < 16; m++) {
        float s = part[m];
#pragma unroll
        for (int msk = 32; msk; msk >>= 1) s += __shfl_xor(s, msk, 64);
        part[m] = s;
    }
    __shared__ float wred[4][16];
    __shared__ float wmat[16];
    if (lane == 0) {
#pragma unroll
        for (int m = 0; m < 16; m++) wred[wave][m] = part[m];
    }
    __syncthreads();
    if (tid == 0) {
        float dv[16], mx = -1e30f;
#pragma unroll
        for (int m = 0; m < 16; m++) {
            dv[m] = (wred[0][m] + wred[1][m] + wred[2][m] + wred[3][m]) * SCALE;
            mx = fmaxf(mx, dv[m]);
        }
        float ssum = 0.f;
#pragma unroll
        for (int m = 0; m < 16; m++) { dv[m] = __expf(dv[m] - mx); ssum += dv[m]; }
        float inv = 1.f / ssum;
#pragma unroll
        for (int m = 0; m < 16; m++) wmat[m] = dv[m] * inv;
    }
    __syncthreads();

    float oacc[8];
#pragma unroll
    for (int j = 0; j < 8; j++) oacc[j] = 0.f;
#pragma unroll
    for (int m = 0; m < 16; m++) {
        float vv[8];
        uint4 v = *reinterpret_cast<const uint4*>(v2 + kbase + (size_t)m * D2048 + d0);
        unpack8(v, vv);
        float w = wmat[m];
#pragma unroll
        for (int j = 0; j < 8; j++) oacc[j] += w * vv[j];
    }
    uint4 p;
    p.x = pack2(oacc[0], oacc[1]);
    p.y = pack2(oacc[2], oacc[3]);
    p.z = pack2(oacc[4], oacc[5]);
    p.w = pack2(oacc[6], oacc[7]);
    *reinterpret_cast<uint4*>(att2 + (size_t)r * D2048 + d0) = p;
}

// ---------------------------------------------------------------------------
// LayerNorm over last dim (2048). One block per row. Writes fp32 + bf16 copy.
// ---------------------------------------------------------------------------
__global__ __launch_bounds__(256) void layernorm_k(const float* __restrict__ x,
                                                   const float* __restrict__ g,
                                                   const float* __restrict__ b,
                                                   float* __restrict__ y,
                                                   u16* __restrict__ ybf) {
    int row = blockIdx.x;
    int tid = threadIdx.x, lane = tid & 63, wave = tid >> 6;
    const float* xr = x + (size_t)row * D2048;
    int j = tid * 8;
    float4 v1 = *reinterpret_cast<const float4*>(xr + j);
    float4 v2 = *reinterpret_cast<const float4*>(xr + j + 4);
    float s  = v1.x + v1.y + v1.z + v1.w + v2.x + v2.y + v2.z + v2.w;
    float s2 = v1.x * v1.x + v1.y * v1.y + v1.z * v1.z + v1.w * v1.w +
               v2.x * v2.x + v2.y * v2.y + v2.z * v2.z + v2.w * v2.w;
#pragma unroll
    for (int msk = 32; msk; msk >>= 1) {
        s  += __shfl_xor(s, msk, 64);
        s2 += __shfl_xor(s2, msk, 64);
    }
    __shared__ float red[4][2];
    if (lane == 0) { red[wave][0] = s; red[wave][1] = s2; }
    __syncthreads();
    s  = red[0][0] + red[1][0] + red[2][0] + red[3][0];
    s2 = red[0][1] + red[1][1] + red[2][1] + red[3][1];
    float mu  = s * (1.f / 2048.f);
    float var = s2 * (1.f / 2048.f) - mu * mu;
    float rs  = __frsqrt_rn(var + 1e-5f);

    float4 g1 = *reinterpret_cast<const float4*>(g + j);
    float4 g2 = *reinterpret_cast<const float4*>(g + j + 4);
    float4 b1 = *reinterpret_cast<const float4*>(b + j);
    float4 b2 = *reinterpret_cast<const float4*>(b + j + 4);
    float o[8];
    o[0] = (v1.x - mu) * rs * g1.x + b1.x;
    o[1] = (v1.y - mu) * rs * g1.y + b1.y;
    o[2] = (v1.z - mu) * rs * g1.z + b1.z;
    o[3] = (v1.w - mu) * rs * g1.w + b1.w;
    o[4] = (v2.x - mu) * rs * g2.x + b2.x;
    o[5] = (v2.y - mu) * rs * g2.y + b2.y;
    o[6] = (v2.z - mu) * rs * g2.z + b2.z;
    o[7] = (v2.w - mu) * rs * g2.w + b2.w;
    float4 o1 = {o[0], o[1], o[2], o[3]};
    float4 o2 = {o[4], o[5], o[6], o[7]};
    float* yr = y + (size_t)row * D2048;
    *reinterpret_cast<float4*>(yr + j)     = o1;
    *reinterpret_cast<float4*>(yr + j + 4) = o2;
    uint4 p;
    p.x = pack2(o[0], o[1]);
    p.y = pack2(o[2], o[3]);
    p.z = pack2(o[4], o[5]);
    p.w = pack2(o[6], o[7]);
    *reinterpret_cast<uint4*>(ybf + (size_t)row * D2048 + j) = p;
}

// ---------------------------------------------------------------------------
static inline void launch_qkv(hipStream_t s, const u16* A, const u16* Wq,
                              const u16* Wk, const u16* Wv, const float* bq,
                              const float* bk, const float* bv, u16* out,
                              int M, int N, int K) {
    dim3 grid(N / 128, M / 128, 3);
    gemm_qkv<<<grid, 256, 0, s>>>(A, Wq, Wk, Wv, bq, bk, bv, out,
                                  (size_t)M * N, M, N, K);
}

extern "C" void kernel_launch(void* const* d_in, const int* in_sizes, int n_in,
                              void* d_out, int out_size, void* d_ws, size_t ws_size,
                              hipStream_t stream) {
    const float* fc      = (const float*)d_in[0];
    const float* nsa_Wq  = (const float*)d_in[1];
    const float* nsa_Wk  = (const float*)d_in[2];
    const float* nsa_Wv  = (const float*)d_in[3];
    const float* nsa_bq  = (const float*)d_in[4];
    const float* nsa_bk  = (const float*)d_in[5];
    const float* nsa_bv  = (const float*)d_in[6];
    const float* nsa_Wih = (const float*)d_in[7];
    const float* nsa_Whh = (const float*)d_in[8];
    const float* nsa_bih = (const float*)d_in[9];
    const float* nsa_bhh = (const float*)d_in[10];
    const float* sa_Wq   = (const float*)d_in[11];
    const float* sa_Wk   = (const float*)d_in[12];
    const float* sa_Wv   = (const float*)d_in[13];
    const float* sa_bq   = (const float*)d_in[14];
    const float* sa_bk   = (const float*)d_in[15];
    const float* sa_bv   = (const float*)d_in[16];
    const float* sa_Wih  = (const float*)d_in[17];
    const float* sa_Whh  = (const float*)d_in[18];
    const float* sa_bih  = (const float*)d_in[19];
    const float* sa_bhh  = (const float*)d_in[20];
    const float* ln_g    = (const float*)d_in[21];
    const float* ln_b    = (const float*)d_in[22];

    float* outF   = (float*)d_out;
    float* out_sa = outF;            // (64,2048)
    float* out_ln = outF + 131072;   // (64,16,2048)

    char* W = (char*)d_ws;
    u16* W_q   = (u16*)(W + 0);          // nsa->sa QKV weights; h1/c1/hbfA alias
    u16* W_k   = (u16*)(W + 8388608);
    u16* W_v   = (u16*)(W + 16777216);
    u16* W_ih  = (u16*)(W + 25165824);   // nsa_Wih -> sa_Wih
    u16* W_hh1 = (u16*)(W + 58720256);   // nsa_Whh
    u16* W_hh2 = (u16*)(W + 92274688);   // sa_Whh
    u16*   Xbf  = (u16*)(W + 125829120); // fc bf16; lnbf alias
    u16*   q0   = (u16*)(W + 131072000); // q0/k0/v0; hbfB alias; q2/k2/v2
    u16*   att1 = (u16*)(W + 146800640); // att1/att2
    u16*   xg   = (u16*)(W + 167772160); // 5120x8192 bf16 (xg2 subset)
    // aliases:
    float* h1    = (float*)(W + 0);         // 1024x2048 f32 (nsa final h, until LN)
    float* c1    = (float*)(W + 8388608);   // 1024x2048 f32
    u16*   hbfA  = (u16*)(W + 16777216);    // 1024x2048 bf16 ping
    u16*   hbfB  = (u16*)(W + 131072000);   // 1024x2048 bf16 pong (dead q0 region)
    u16*   lnbf  = Xbf;
    u16*   q2    = q0;
    u16*   att2  = att1;
    float* c2    = (float*)(W + 148373504); // 64x2048 f32 (dead att2 tail region)
    u16*   h2bfA = (u16*)(W + 148897792);   // 64x2048 bf16 ping
    u16*   h2bfB = (u16*)(W + 149422080);   // 64x2048 bf16 pong

    // 0) convert fc + nsa weights + sa_Whh to bf16
    {
        CvtArgs a{};
        a.src[0] = fc;      a.dst[0] = Xbf;   a.n4[0] = 655360;
        a.src[1] = nsa_Wq;  a.dst[1] = W_q;   a.n4[1] = 1048576;
        a.src[2] = nsa_Wk;  a.dst[2] = W_k;   a.n4[2] = 1048576;
        a.src[3] = nsa_Wv;  a.dst[3] = W_v;   a.n4[3] = 1048576;
        a.src[4] = nsa_Wih; a.dst[4] = W_ih;  a.n4[4] = 4194304;
        a.src[5] = nsa_Whh; a.dst[5] = W_hh1; a.n4[5] = 4194304;
        a.src[6] = sa_Whh;  a.dst[6] = W_hh2; a.n4[6] = 4194304;
        a.nseg = 7;
        cvt_multi<<<2048, 256, 0, stream>>>(a);
    }

    // 1) nsa QKV on the 1280 unique rows (z=3, 480 blocks)
    launch_qkv(stream, Xbf, W_q, W_k, W_v, nsa_bq, nsa_bk, nsa_bv, q0, 1280, 2048, 2048);

    // 2) windowed attention
    attn_win5<<<1024, 256, 0, stream>>>(q0, q0 + 2621440, q0 + 5242880, att1);

    // 3) xg for ALL 5 steps: one M=5120 8-phase GEMM (640 blocks), bf16 out
    gemm256<true><<<dim3(32, 20), 512, 0, stream>>>(att1, 2048, W_ih, xg,
                                                    5120, 8192, 2048);

    // 4) nsa LSTM over 5 steps; steps 1..4 = fused GEMM+gate (512 blocks)
    lstm_gate0<<<2048, 256, 0, stream>>>(xg, 40960, nsa_bih, nsa_bhh, c1, hbfA, 1024);
    {
        u16* hin = hbfA;
        for (int t = 1; t < 5; ++t) {
            u16* hout = (t & 1) ? hbfB : hbfA;
            if (t == 4)
                gemm_gate128<true><<<dim3(64, 8), 256, 0, stream>>>(
                    hin, W_hh1, xg + (size_t)t * 8192, 40960, nsa_bih, nsa_bhh,
                    c1, hout, h1, 2048);
            else
                gemm_gate128<false><<<dim3(64, 8), 256, 0, stream>>>(
                    hin, W_hh1, xg + (size_t)t * 8192, 40960, nsa_bih, nsa_bhh,
                    c1, hout, nullptr, 2048);
            hin = hout;
        }
    }

    // 5) LayerNorm -> output 1 (fp32) + bf16 copy for stage 2
    layernorm_k<<<1024, 256, 0, stream>>>(h1, ln_g, ln_b, out_ln, lnbf);

    // 5b) convert sa single-use weights into the (now dead) nsa slots
    {
        CvtArgs a{};
        a.src[0] = sa_Wq;  a.dst[0] = W_q;  a.n4[0] = 1048576;
        a.src[1] = sa_Wk;  a.dst[1] = W_k;  a.n4[1] = 1048576;
        a.src[2] = sa_Wv;  a.dst[2] = W_v;  a.n4[2] = 1048576;
        a.src[3] = sa_Wih; a.dst[3] = W_ih; a.n4[3] = 4194304;
        a.nseg = 4;
        cvt_multi<<<2048, 256, 0, stream>>>(a);
    }

    // 6) sa QKV (z=3, 384 blocks)
    launch_qkv(stream, lnbf, W_q, W_k, W_v, sa_bq, sa_bk, sa_bv, q2, 1024, 2048, 2048);

    // 7) seq-16 attention
    attn_seq16<<<1024, 256, 0, stream>>>(q2, q2 + 2097152, q2 + 4194304, att2);

    // 8) xg2 = att2 @ saWih^T: 128^2 tile -> 512 blocks (full GPU)
    gemm128_bf<<<dim3(64, 8), 256, 0, stream>>>(att2, W_ih, xg, 1024, 8192, 2048);

    // 9) sa LSTM over 16 steps; steps 1..15 = fused GEMM+gate v2 (256 blocks)
    lstm_gate0<<<128, 256, 0, stream>>>(xg, 131072, sa_bih, sa_bhh, c2, h2bfA, 64);
    {
        u16* hin = h2bfA;
        for (int t = 1; t < 16; ++t) {
            u16* hout = (t & 1) ? h2bfB : h2bfA;
            gemm_gate64v2<<<dim3(256), 256, 0, stream>>>(
                hin, W_hh2, xg + (size_t)t * 8192, 131072, sa_bih, sa_bhh,
                c2, hout, (t == 15) ? out_sa : nullptr, 2048);
            hin = hout;
        }
    }
}